// Round 1
// 550.469 us; speedup vs baseline: 1.0961x; 1.0961x over previous
//
#include <hip/hip_runtime.h>
#include <stdint.h>

typedef __attribute__((ext_vector_type(8))) short s16x8;    // bf16 MFMA A/B frag (4 VGPRs)
typedef __attribute__((ext_vector_type(4))) float f32x4;    // MFMA C/D frag
typedef __attribute__((ext_vector_type(4))) unsigned short us4;
typedef __attribute__((ext_vector_type(8))) unsigned short us8;

// ---- bf16 round-to-nearest-even (inputs are finite normals) ----
__device__ inline unsigned short bf_rne(float f) {
    union { float f; uint32_t u; } v; v.f = f;
    uint32_t u = v.u;
    u += 0x7FFFu + ((u >> 16) & 1u);
    return (unsigned short)(u >> 16);
}

// async global->LDS, 16B per lane; LDS dst is wave-uniform base + lane*16
#define GLD_LDS16(gp, lp)                                                     \
    __builtin_amdgcn_global_load_lds(                                         \
        (const __attribute__((address_space(1))) void*)(gp),                  \
        (__attribute__((address_space(3))) void*)(lp), 16, 0, 0)

// ---------------- Fused prologue ----------------
// blocks [0,512):    prep — adapted = W + B@A -> bf16, scale = mag/rownorm, 8 rows/block
// blocks [512,2560): cvt — x fp32 -> bf16, grid-stride, 16 elems/iter/thread, us8 (16B) stores
__global__ __launch_bounds__(256) void prologue_kernel(
    const float4* __restrict__ x4, us8* __restrict__ xbf8,
    const float4* __restrict__ W4,
    const float4* __restrict__ A4,   // [16][1024] float4
    const float* __restrict__ B,     // [4096][16]
    const float* __restrict__ mag,   // [4096]
    unsigned short* __restrict__ wbf,
    float* __restrict__ scale) {
    const int tid = threadIdx.x;
    if (blockIdx.x < 512) {
        const int m0 = blockIdx.x * 8;
        __shared__ float Bsh[8][16];
        __shared__ float red[32];
        if (tid < 128) Bsh[tid >> 4][tid & 15] = B[m0 * 16 + tid];
        __syncthreads();
        float ss[8] = {};
        for (int c = tid; c < 1024; c += 256) {
            float4 a[16];
#pragma unroll
            for (int r = 0; r < 16; ++r) a[r] = A4[r * 1024 + c];
#pragma unroll
            for (int i = 0; i < 8; ++i) {
                float4 w = W4[(size_t)(m0 + i) * 1024 + c];
#pragma unroll
                for (int r = 0; r < 16; ++r) {
                    const float br = Bsh[i][r];
                    w.x += br * a[r].x; w.y += br * a[r].y;
                    w.z += br * a[r].z; w.w += br * a[r].w;
                }
                ss[i] += w.x * w.x + w.y * w.y + w.z * w.z + w.w * w.w;
                us4 o; o[0] = bf_rne(w.x); o[1] = bf_rne(w.y);
                o[2] = bf_rne(w.z); o[3] = bf_rne(w.w);
                *(us4*)&wbf[(size_t)(m0 + i) * 4096 + c * 4] = o;
            }
        }
        const int lane = tid & 63, wv = tid >> 6;
#pragma unroll
        for (int i = 0; i < 8; ++i) {
            float v = ss[i];
#pragma unroll
            for (int off = 32; off > 0; off >>= 1) v += __shfl_down(v, off, 64);
            if (lane == 0) red[wv * 8 + i] = v;
        }
        __syncthreads();
        if (tid < 8) {
            float tot = red[tid] + red[8 + tid] + red[16 + tid] + red[24 + tid];
            scale[m0 + tid] = mag[m0 + tid] / sqrtf(tot);
        }
    } else {
        // cvt: 4,194,304 us8 units; 524,288 threads; exactly 8 units/thread
        const size_t stride = (size_t)2048 * 256;
        size_t p = (size_t)(blockIdx.x - 512) * 256 + tid;
#pragma unroll 2
        for (int it = 0; it < 8; ++it, p += stride) {
            float4 a = x4[2 * p];
            float4 b = x4[2 * p + 1];
            us8 o;
            o[0] = bf_rne(a.x); o[1] = bf_rne(a.y);
            o[2] = bf_rne(a.z); o[3] = bf_rne(a.w);
            o[4] = bf_rne(b.x); o[5] = bf_rne(b.y);
            o[6] = bf_rne(b.z); o[7] = bf_rne(b.w);
            xbf8[p] = o;
        }
    }
}

// ---------------- GEMM: C[8192][4096] = xbf @ wbf^T * scale ----------------
// 256x256 tile, BK=64, 8 waves (2M x 4N), 4-phase-per-K-tile counted-vmcnt pipeline
// (T2 XOR swizzle + T3/T4 counted vmcnt + T5 setprio). 128 KiB LDS double buffer.
// Slot discipline (race-free by barriers):
//   tile t phases consume buf[t&1]; B-frags read ONLY in ph0 (held in regs);
//   ph0/ph1 stage (t+1).A into buf[~cur].A (freed by t-1, >=2 barriers back);
//   ph2/ph3 stage (t+2).B into buf[cur].B  (read finished in ph0, 2 barriers back);
//   vmcnt(4) once per tile (2 half-tiles in flight), vmcnt(0) only at t=62 tail.
__global__ __launch_bounds__(512, 2) void dora_gemm(
    const unsigned short* __restrict__ xbf,   // [8192][4096] bf16
    const unsigned short* __restrict__ wbf,   // [4096][4096] bf16
    const float* __restrict__ scale,          // [4096]
    float* __restrict__ out) {                // [8192][4096] fp32
    constexpr int TSZ = 256 * 64;             // shorts per K-tile buffer (32 KiB)
    __shared__ __align__(16) unsigned short As[2 * TSZ];
    __shared__ __align__(16) unsigned short Bs[2 * TSZ];

    const int tid  = threadIdx.x;
    const int lane = tid & 63;
    const int w    = tid >> 6;     // wave 0..7
    const int wm   = w >> 2;       // 0..1  (M half: 128 rows)
    const int wn   = w & 3;        // 0..3  (N quarter: 64 cols)

    // bijective XCD-chunked swizzle: 512 blocks = 8 XCDs x 64; N-fast within XCD
    const int L = (blockIdx.x & 7) * 64 + (blockIdx.x >> 3);
    const int tileM = (L >> 4) * 256;   // 32 M-tiles
    const int tileN = (L & 15) * 256;   // 16 N-tiles

    // staging: wave w call j covers rows w*16+j*8 .. +8 of a 128-row half
    // XOR swizzle: physical 16B chunk p of row r holds logical chunk p ^ (r&7)
    const int i8 = lane >> 3;
    const int lc = (lane & 7) ^ i8;     // pre-swizzled global source chunk

    const unsigned short* gA = xbf + (size_t)tileM * 4096;
    const unsigned short* gB = wbf + (size_t)tileN * 4096;

    auto stage = [&](const unsigned short* __restrict__ g,
                     unsigned short* lbase, int T, int h) {
#pragma unroll
        for (int j = 0; j < 2; ++j) {
            const int r0 = h * 128 + w * 16 + j * 8;   // wave-uniform
            GLD_LDS16(g + (size_t)(r0 + i8) * 4096 + T * 64 + lc * 8,
                      lbase + r0 * 64);
        }
    };

    // pipeline prologue: tile0 (A+B) -> buf0, tile1 B -> buf1; 12 loads/wave
    stage(gA, As, 0, 0); stage(gA, As, 0, 1);
    stage(gB, Bs, 0, 0); stage(gB, Bs, 0, 1);
    stage(gB, Bs + TSZ, 1, 0); stage(gB, Bs + TSZ, 1, 1);
    asm volatile("s_waitcnt vmcnt(4)" ::: "memory");   // tile0 landed; t1.B in flight
    __builtin_amdgcn_s_barrier();

    const int q   = lane >> 4;
    const int c15 = lane & 15;
    f32x4 acc[8][4] = {};

#pragma unroll 2
    for (int t = 0; t < 64; ++t) {
        const int cur = t & 1;
        unsigned short* Ac = As + cur * TSZ;
        unsigned short* Bc = Bs + cur * TSZ;
        unsigned short* An = As + (cur ^ 1) * TSZ;

        s16x8 bfrag[4][2];
#pragma unroll
        for (int ph = 0; ph < 4; ++ph) {
            // ds-reads for this phase (B once per tile, held in regs)
            if (ph == 0) {
#pragma unroll
                for (int nt = 0; nt < 4; ++nt) {
                    const int row = wn * 64 + nt * 16 + c15;
#pragma unroll
                    for (int kc = 0; kc < 2; ++kc) {
                        const int phys = (kc * 4 + q) ^ (row & 7);
                        bfrag[nt][kc] = *(const s16x8*)&Bc[row * 64 + phys * 8];
                    }
                }
            }
            s16x8 af[2][2];
#pragma unroll
            for (int i = 0; i < 2; ++i) {
                const int row = wm * 128 + (ph * 2 + i) * 16 + c15;
#pragma unroll
                for (int kc = 0; kc < 2; ++kc) {
                    const int phys = (kc * 4 + q) ^ (row & 7);
                    af[i][kc] = *(const s16x8*)&Ac[row * 64 + phys * 8];
                }
            }
            // staged prefetch: one half-tile (2 gld_lds/wave) per phase
            if (ph == 0 && t < 63) stage(gA, An, t + 1, 0);
            if (ph == 1 && t < 63) stage(gA, An, t + 1, 1);
            if (ph == 2 && t < 62) stage(gB, Bc, t + 2, 0);
            if (ph == 3 && t < 62) stage(gB, Bc, t + 2, 1);

            __builtin_amdgcn_s_barrier();
            asm volatile("s_waitcnt lgkmcnt(0)" ::: "memory");
            __builtin_amdgcn_s_setprio(1);
#pragma unroll
            for (int i = 0; i < 2; ++i)
#pragma unroll
                for (int nt = 0; nt < 4; ++nt)
#pragma unroll
                    for (int kc = 0; kc < 2; ++kc)
                        acc[ph * 2 + i][nt] = __builtin_amdgcn_mfma_f32_16x16x32_bf16(
                            af[i][kc], bfrag[nt][kc], acc[ph * 2 + i][nt], 0, 0, 0);
            __builtin_amdgcn_s_setprio(0);
            if (ph == 3) {
                if (t < 62) { asm volatile("s_waitcnt vmcnt(4)" ::: "memory"); }
                else        { asm volatile("s_waitcnt vmcnt(0)" ::: "memory"); }
            }
            __builtin_amdgcn_s_barrier();
        }
    }

    // epilogue: C/D layout col=lane&15, row=(lane>>4)*4+reg ; scale by mag/norm
#pragma unroll
    for (int nt = 0; nt < 4; ++nt) {
        const int col = tileN + wn * 64 + nt * 16 + c15;
        const float s = scale[col];
#pragma unroll
        for (int mt = 0; mt < 8; ++mt) {
            const int row0 = tileM + wm * 128 + mt * 16 + q * 4;
#pragma unroll
            for (int r = 0; r < 4; ++r)
                out[(size_t)(row0 + r) * 4096 + col] = acc[mt][nt][r] * s;
        }
    }
}

extern "C" void kernel_launch(void* const* d_in, const int* in_sizes, int n_in,
                              void* d_out, int out_size, void* d_ws, size_t ws_size,
                              hipStream_t stream) {
    const float* x   = (const float*)d_in[0];   // [4,2048,4096]
    const float* W   = (const float*)d_in[1];   // [4096,4096]
    const float* A   = (const float*)d_in[2];   // [16,4096]
    const float* B   = (const float*)d_in[3];   // [4096,16]
    const float* mag = (const float*)d_in[4];   // [4096]
    float* out = (float*)d_out;

    const size_t XBF_BYTES = (size_t)8192 * 4096 * 2;  // 67,108,864
    const size_t WBF_BYTES = (size_t)4096 * 4096 * 2;  // 33,554,432
    const size_t NEEDED = XBF_BYTES + WBF_BYTES + 4096 * sizeof(float);
    if (ws_size < NEEDED) return;

    unsigned short* xbf = (unsigned short*)d_ws;
    unsigned short* wbf = (unsigned short*)((char*)d_ws + XBF_BYTES);
    float* scale = (float*)((char*)d_ws + XBF_BYTES + WBF_BYTES);

    prologue_kernel<<<2560, 256, 0, stream>>>((const float4*)x, (us8*)xbf,
                                              (const float4*)W, (const float4*)A,
                                              B, mag, wbf, scale);
    dora_gemm<<<512, 512, 0, stream>>>(xbf, wbf, scale, out);
}

// Round 2
// 539.563 us; speedup vs baseline: 1.1183x; 1.0202x over previous
//
#include <hip/hip_runtime.h>
#include <stdint.h>

typedef __attribute__((ext_vector_type(8))) short s16x8;    // bf16 MFMA A/B frag (4 VGPRs)
typedef __attribute__((ext_vector_type(4))) float f32x4;    // MFMA C/D frag
typedef __attribute__((ext_vector_type(4))) unsigned short us4;

// ---- bf16 round-to-nearest-even (inputs are finite normals) ----
__device__ inline unsigned short bf_rne(float f) {
    union { float f; uint32_t u; } v; v.f = f;
    uint32_t u = v.u;
    u += 0x7FFFu + ((u >> 16) & 1u);
    return (unsigned short)(u >> 16);
}

// async global->LDS, 16B per lane; LDS dst is wave-uniform base + lane*16
#define GLD_LDS16(gp, lp)                                                     \
    __builtin_amdgcn_global_load_lds(                                         \
        (const __attribute__((address_space(1))) void*)(gp),                  \
        (__attribute__((address_space(3))) void*)(lp), 16, 0, 0)

// ---------------- prep: adapted = W + B@A -> bf16, scale = mag/rownorm ----------------
// 1024 blocks x 256 thr, 4 rows/block, rank-blocked (VGPR ~50 -> high occupancy)
__global__ __launch_bounds__(256) void prep_kernel(
    const float4* __restrict__ W4,
    const float4* __restrict__ A4,   // [16][1024] float4
    const float* __restrict__ B,     // [4096][16]
    const float* __restrict__ mag,   // [4096]
    unsigned short* __restrict__ wbf,
    float* __restrict__ scale) {
    const int tid = threadIdx.x;
    const int m0 = blockIdx.x * 4;
    __shared__ float4 Bsh4[4][4];    // 4 rows x 16 floats
    __shared__ float red[16];
    if (tid < 64) ((float*)Bsh4)[tid] = B[m0 * 16 + tid];
    __syncthreads();
    float ss[4] = {};
    for (int c = tid; c < 1024; c += 256) {   // 4 iters
        float4 w[4];
#pragma unroll
        for (int i = 0; i < 4; ++i) w[i] = W4[(size_t)(m0 + i) * 1024 + c];
#pragma unroll
        for (int rg = 0; rg < 4; ++rg) {
            float4 a[4];
#pragma unroll
            for (int r = 0; r < 4; ++r) a[r] = A4[(rg * 4 + r) * 1024 + c];
#pragma unroll
            for (int i = 0; i < 4; ++i) {
                const float4 b = Bsh4[i][rg];
                w[i].x += b.x * a[0].x + b.y * a[1].x + b.z * a[2].x + b.w * a[3].x;
                w[i].y += b.x * a[0].y + b.y * a[1].y + b.z * a[2].y + b.w * a[3].y;
                w[i].z += b.x * a[0].z + b.y * a[1].z + b.z * a[2].z + b.w * a[3].z;
                w[i].w += b.x * a[0].w + b.y * a[1].w + b.z * a[2].w + b.w * a[3].w;
            }
        }
#pragma unroll
        for (int i = 0; i < 4; ++i) {
            ss[i] += w[i].x * w[i].x + w[i].y * w[i].y + w[i].z * w[i].z + w[i].w * w[i].w;
            us4 o; o[0] = bf_rne(w[i].x); o[1] = bf_rne(w[i].y);
            o[2] = bf_rne(w[i].z); o[3] = bf_rne(w[i].w);
            *(us4*)&wbf[(size_t)(m0 + i) * 4096 + c * 4] = o;
        }
    }
    const int lane = tid & 63, wv = tid >> 6;
#pragma unroll
    for (int i = 0; i < 4; ++i) {
        float v = ss[i];
#pragma unroll
        for (int off = 32; off > 0; off >>= 1) v += __shfl_down(v, off, 64);
        if (lane == 0) red[wv * 4 + i] = v;
    }
    __syncthreads();
    if (tid < 4) {
        float tot = red[tid] + red[4 + tid] + red[8 + tid] + red[12 + tid];
        scale[m0 + tid] = mag[m0 + tid] / sqrtf(tot);
    }
}

// ---------------- cvt: x fp32 -> bf16, unit-stride float4 -> us4 (8B) ----------------
__global__ __launch_bounds__(256) void cvt_kernel(
    const float4* __restrict__ x4, us4* __restrict__ xbf4) {
    const size_t base = (size_t)blockIdx.x * 1024 + threadIdx.x;
#pragma unroll
    for (int j = 0; j < 4; ++j) {
        const size_t idx = base + j * 256;
        float4 a = x4[idx];
        us4 o;
        o[0] = bf_rne(a.x); o[1] = bf_rne(a.y);
        o[2] = bf_rne(a.z); o[3] = bf_rne(a.w);
        xbf4[idx] = o;
    }
}

// ---------------- GEMM: C[8192][4096] = xbf @ wbf^T * scale ----------------
// 256x256 tile, BK=64, 8 waves (2M x 4N), 4-phase-per-K-tile counted-vmcnt pipeline.
// Slot discipline (race-free by barriers, all dest-overwrites >= 1 full barrier after
// the last drained read of that region):
//   tile t consumes buf[t&1]; B-frags read ONLY in ph0 (held in regs);
//   ph0 stages BOTH halves of (t+1).A into buf[~cur].A  (freed by t-1.ph3);
//   ph1 stages (t+2).B.h0, ph2 stages (t+2).B.h1 into buf[cur].B (freed by t.ph0);
//   ph3: vmcnt(4) retires exactly {B(t+1), A(t+1)}; A has 3+ phases of latency cover.
__global__ __launch_bounds__(512, 2) void dora_gemm(
    const unsigned short* __restrict__ xbf,   // [8192][4096] bf16
    const unsigned short* __restrict__ wbf,   // [4096][4096] bf16
    const float* __restrict__ scale,          // [4096]
    float* __restrict__ out) {                // [8192][4096] fp32
    constexpr int TSZ = 256 * 64;             // shorts per K-tile buffer (32 KiB)
    __shared__ __align__(16) unsigned short As[2 * TSZ];
    __shared__ __align__(16) unsigned short Bs[2 * TSZ];

    const int tid  = threadIdx.x;
    const int lane = tid & 63;
    const int w    = tid >> 6;     // wave 0..7
    const int wm   = w >> 2;       // 0..1  (M half: 128 rows)
    const int wn   = w & 3;        // 0..3  (N quarter: 64 cols)

    // bijective XCD-chunked swizzle: 512 blocks = 8 XCDs x 64; N-fast within XCD
    const int L = (blockIdx.x & 7) * 64 + (blockIdx.x >> 3);
    const int tileM = (L >> 4) * 256;   // 32 M-tiles
    const int tileN = (L & 15) * 256;   // 16 N-tiles

    // staging: wave w call j covers rows h*128 + w*16 + j*8 .. +8
    // XOR swizzle: physical 16B chunk p of row r holds logical chunk p ^ (r&7)
    const int i8 = lane >> 3;
    const int lc = (lane & 7) ^ i8;     // pre-swizzled global source chunk

    const unsigned short* gA = xbf + (size_t)tileM * 4096;
    const unsigned short* gB = wbf + (size_t)tileN * 4096;

    auto stage = [&](const unsigned short* __restrict__ g,
                     unsigned short* lbase, int T, int h) {
#pragma unroll
        for (int j = 0; j < 2; ++j) {
            const int r0 = h * 128 + w * 16 + j * 8;   // wave-uniform
            GLD_LDS16(g + (size_t)(r0 + i8) * 4096 + T * 64 + lc * 8,
                      lbase + r0 * 64);
        }
    };

    // pipeline prologue: tile0 (A+B) -> buf0, tile1 B -> buf1; 12 loads/wave
    stage(gA, As, 0, 0); stage(gA, As, 0, 1);
    stage(gB, Bs, 0, 0); stage(gB, Bs, 0, 1);
    stage(gB, Bs + TSZ, 1, 0); stage(gB, Bs + TSZ, 1, 1);
    asm volatile("s_waitcnt vmcnt(4)" ::: "memory");   // tile0 landed; t1.B in flight
    __builtin_amdgcn_s_barrier();

    const int q   = lane >> 4;
    const int c15 = lane & 15;
    f32x4 acc[8][4] = {};

#pragma unroll 2
    for (int t = 0; t < 64; ++t) {
        const int cur = t & 1;
        unsigned short* Ac = As + cur * TSZ;
        unsigned short* Bc = Bs + cur * TSZ;
        unsigned short* An = As + (cur ^ 1) * TSZ;

        s16x8 bfrag[4][2];
#pragma unroll
        for (int ph = 0; ph < 4; ++ph) {
            // ds-reads for this phase (B once per tile, held in regs)
            if (ph == 0) {
#pragma unroll
                for (int nt = 0; nt < 4; ++nt) {
                    const int row = wn * 64 + nt * 16 + c15;
#pragma unroll
                    for (int kc = 0; kc < 2; ++kc) {
                        const int phys = (kc * 4 + q) ^ (row & 7);
                        bfrag[nt][kc] = *(const s16x8*)&Bc[row * 64 + phys * 8];
                    }
                }
            }
            s16x8 af[2][2];
#pragma unroll
            for (int i = 0; i < 2; ++i) {
                const int row = wm * 128 + (ph * 2 + i) * 16 + c15;
#pragma unroll
                for (int kc = 0; kc < 2; ++kc) {
                    const int phys = (kc * 4 + q) ^ (row & 7);
                    af[i][kc] = *(const s16x8*)&Ac[row * 64 + phys * 8];
                }
            }
            // staged prefetch: A(t+1) both halves at ph0 (deep cover for ph3 wait);
            // B(t+2) halves at ph1/ph2 (dest freed by t.ph0's drained reads)
            if (ph == 0 && t < 63) { stage(gA, An, t + 1, 0); stage(gA, An, t + 1, 1); }
            if (ph == 1 && t < 62) stage(gB, Bc, t + 2, 0);
            if (ph == 2 && t < 62) stage(gB, Bc, t + 2, 1);

            __builtin_amdgcn_s_barrier();
            asm volatile("s_waitcnt lgkmcnt(0)" ::: "memory");
            __builtin_amdgcn_s_setprio(1);
#pragma unroll
            for (int i = 0; i < 2; ++i)
#pragma unroll
                for (int nt = 0; nt < 4; ++nt)
#pragma unroll
                    for (int kc = 0; kc < 2; ++kc)
                        acc[ph * 2 + i][nt] = __builtin_amdgcn_mfma_f32_16x16x32_bf16(
                            af[i][kc], bfrag[nt][kc], acc[ph * 2 + i][nt], 0, 0, 0);
            __builtin_amdgcn_s_setprio(0);
            if (ph == 3) {
                if (t < 62) { asm volatile("s_waitcnt vmcnt(4)" ::: "memory"); }
                else        { asm volatile("s_waitcnt vmcnt(0)" ::: "memory"); }
            }
            __builtin_amdgcn_s_barrier();
        }
    }

    // epilogue: C/D layout col=lane&15, row=(lane>>4)*4+reg ; scale by mag/norm
#pragma unroll
    for (int nt = 0; nt < 4; ++nt) {
        const int col = tileN + wn * 64 + nt * 16 + c15;
        const float s = scale[col];
#pragma unroll
        for (int mt = 0; mt < 8; ++mt) {
            const int row0 = tileM + wm * 128 + mt * 16 + q * 4;
#pragma unroll
            for (int r = 0; r < 4; ++r)
                out[(size_t)(row0 + r) * 4096 + col] = acc[mt][nt][r] * s;
        }
    }
}

extern "C" void kernel_launch(void* const* d_in, const int* in_sizes, int n_in,
                              void* d_out, int out_size, void* d_ws, size_t ws_size,
                              hipStream_t stream) {
    const float* x   = (const float*)d_in[0];   // [4,2048,4096]
    const float* W   = (const float*)d_in[1];   // [4096,4096]
    const float* A   = (const float*)d_in[2];   // [16,4096]
    const float* B   = (const float*)d_in[3];   // [4096,16]
    const float* mag = (const float*)d_in[4];   // [4096]
    float* out = (float*)d_out;

    const size_t XBF_BYTES = (size_t)8192 * 4096 * 2;  // 67,108,864
    const size_t WBF_BYTES = (size_t)4096 * 4096 * 2;  // 33,554,432
    const size_t NEEDED = XBF_BYTES + WBF_BYTES + 4096 * sizeof(float);
    if (ws_size < NEEDED) return;

    unsigned short* xbf = (unsigned short*)d_ws;
    unsigned short* wbf = (unsigned short*)((char*)d_ws + XBF_BYTES);
    float* scale = (float*)((char*)d_ws + XBF_BYTES + WBF_BYTES);

    cvt_kernel<<<8192, 256, 0, stream>>>((const float4*)x, (us4*)xbf);
    prep_kernel<<<1024, 256, 0, stream>>>((const float4*)W, (const float4*)A,
                                          B, mag, wbf, scale);
    dora_gemm<<<512, 512, 0, stream>>>(xbf, wbf, scale, out);
}

// Round 3
// 533.092 us; speedup vs baseline: 1.1319x; 1.0121x over previous
//
#include <hip/hip_runtime.h>
#include <stdint.h>

typedef __attribute__((ext_vector_type(8))) short s16x8;    // bf16 MFMA A/B frag (4 VGPRs)
typedef __attribute__((ext_vector_type(4))) float f32x4;    // MFMA C/D frag
typedef __attribute__((ext_vector_type(4))) unsigned short us4;

// ---- bf16 round-to-nearest-even (inputs are finite normals) ----
__device__ inline unsigned short bf_rne(float f) {
    union { float f; uint32_t u; } v; v.f = f;
    uint32_t u = v.u;
    u += 0x7FFFu + ((u >> 16) & 1u);
    return (unsigned short)(u >> 16);
}

// async global->LDS, 16B per lane; LDS dst is wave-uniform base + lane*16
#define GLD_LDS16(gp, lp)                                                     \
    __builtin_amdgcn_global_load_lds(                                         \
        (const __attribute__((address_space(1))) void*)(gp),                  \
        (__attribute__((address_space(3))) void*)(lp), 16, 0, 0)

// ---------------- prep: adapted = W + B@A -> bf16, scale = mag/rownorm ----------------
// 1024 blocks x 256 thr, 4 rows/block, rank-blocked
__global__ __launch_bounds__(256) void prep_kernel(
    const float4* __restrict__ W4,
    const float4* __restrict__ A4,   // [16][1024] float4
    const float* __restrict__ B,     // [4096][16]
    const float* __restrict__ mag,   // [4096]
    unsigned short* __restrict__ wbf,
    float* __restrict__ scale) {
    const int tid = threadIdx.x;
    const int m0 = blockIdx.x * 4;
    __shared__ float4 Bsh4[4][4];    // 4 rows x 16 floats
    __shared__ float red[16];
    if (tid < 64) ((float*)Bsh4)[tid] = B[m0 * 16 + tid];
    __syncthreads();
    float ss[4] = {};
    for (int c = tid; c < 1024; c += 256) {   // 4 iters
        float4 w[4];
#pragma unroll
        for (int i = 0; i < 4; ++i) w[i] = W4[(size_t)(m0 + i) * 1024 + c];
#pragma unroll
        for (int rg = 0; rg < 4; ++rg) {
            float4 a[4];
#pragma unroll
            for (int r = 0; r < 4; ++r) a[r] = A4[(rg * 4 + r) * 1024 + c];
#pragma unroll
            for (int i = 0; i < 4; ++i) {
                const float4 b = Bsh4[i][rg];
                w[i].x += b.x * a[0].x + b.y * a[1].x + b.z * a[2].x + b.w * a[3].x;
                w[i].y += b.x * a[0].y + b.y * a[1].y + b.z * a[2].y + b.w * a[3].y;
                w[i].z += b.x * a[0].z + b.y * a[1].z + b.z * a[2].z + b.w * a[3].z;
                w[i].w += b.x * a[0].w + b.y * a[1].w + b.z * a[2].w + b.w * a[3].w;
            }
        }
#pragma unroll
        for (int i = 0; i < 4; ++i) {
            ss[i] += w[i].x * w[i].x + w[i].y * w[i].y + w[i].z * w[i].z + w[i].w * w[i].w;
            us4 o; o[0] = bf_rne(w[i].x); o[1] = bf_rne(w[i].y);
            o[2] = bf_rne(w[i].z); o[3] = bf_rne(w[i].w);
            *(us4*)&wbf[(size_t)(m0 + i) * 4096 + c * 4] = o;
        }
    }
    const int lane = tid & 63, wv = tid >> 6;
#pragma unroll
    for (int i = 0; i < 4; ++i) {
        float v = ss[i];
#pragma unroll
        for (int off = 32; off > 0; off >>= 1) v += __shfl_down(v, off, 64);
        if (lane == 0) red[wv * 4 + i] = v;
    }
    __syncthreads();
    if (tid < 4) {
        float tot = red[tid] + red[4 + tid] + red[8 + tid] + red[12 + tid];
        scale[m0 + tid] = mag[m0 + tid] / sqrtf(tot);
    }
}

// ---------------- cvt: x fp32 -> bf16, unit-stride float4 -> us4 (8B) ----------------
__global__ __launch_bounds__(256) void cvt_kernel(
    const float4* __restrict__ x4, us4* __restrict__ xbf4) {
    const size_t base = (size_t)blockIdx.x * 1024 + threadIdx.x;
#pragma unroll
    for (int j = 0; j < 4; ++j) {
        const size_t idx = base + j * 256;
        float4 a = x4[idx];
        us4 o;
        o[0] = bf_rne(a.x); o[1] = bf_rne(a.y);
        o[2] = bf_rne(a.z); o[3] = bf_rne(a.w);
        xbf4[idx] = o;
    }
}

// ---------------- GEMM: C[8192][4096] = xbf @ wbf^T * scale ----------------
// 256x256 tile, BK=64, 8 waves (2M x 4N). TWO barriers per K-tile:
//   BAR_mid: after quadrant-0 MFMA (all waves' B-frag ds_reads provably retired,
//            since q0 consumes them and LDS retires in-order) -> safe to overwrite
//            buf[cur].B with B(t+2).
//   BAR_end: after counted vmcnt -> buf[next] (A(t+1),B(t+1)) landed for all waves.
// Everything in between (4 gld_lds, 20 ds_read_b128, 64 MFMA) is compiler-scheduled;
// waves de-phase so LDS-read bursts overlap other waves' MFMA bursts.
// vmcnt invariant (per wave, steady state): after BAR_end(t) only B(t+2)x4 in flight;
//   A(t+1),B(t+1) retired. Tail: vmcnt(0) at t>=62.
__global__ __launch_bounds__(512, 2) void dora_gemm(
    const unsigned short* __restrict__ xbf,   // [8192][4096] bf16
    const unsigned short* __restrict__ wbf,   // [4096][4096] bf16
    const float* __restrict__ scale,          // [4096]
    float* __restrict__ out) {                // [8192][4096] fp32
    constexpr int TSZ = 256 * 64;             // shorts per K-tile buffer (32 KiB)
    __shared__ __align__(16) unsigned short As[2 * TSZ];
    __shared__ __align__(16) unsigned short Bs[2 * TSZ];

    const int tid  = threadIdx.x;
    const int lane = tid & 63;
    const int w    = tid >> 6;     // wave 0..7
    const int wm   = w >> 2;       // 0..1  (M half: 128 rows)
    const int wn   = w & 3;        // 0..3  (N quarter: 64 cols)

    // bijective XCD-chunked swizzle: 512 blocks = 8 XCDs x 64; N-fast within XCD
    const int L = (blockIdx.x & 7) * 64 + (blockIdx.x >> 3);
    const int tileM = (L >> 4) * 256;   // 32 M-tiles
    const int tileN = (L & 15) * 256;   // 16 N-tiles

    // staging: wave w call j covers rows h*128 + w*16 + j*8 .. +8
    // XOR swizzle: physical 16B chunk p of row r holds logical chunk p ^ (r&7)
    const int i8 = lane >> 3;
    const int lc = (lane & 7) ^ i8;     // pre-swizzled global source chunk

    const unsigned short* gA = xbf + (size_t)tileM * 4096;
    const unsigned short* gB = wbf + (size_t)tileN * 4096;

    auto stage = [&](const unsigned short* __restrict__ g,
                     unsigned short* lbase, int T, int h) {
#pragma unroll
        for (int j = 0; j < 2; ++j) {
            const int r0 = h * 128 + w * 16 + j * 8;   // wave-uniform
            GLD_LDS16(g + (size_t)(r0 + i8) * 4096 + T * 64 + lc * 8,
                      lbase + r0 * 64);
        }
    };

    // pipeline prologue: tile0 (A+B) -> buf0, tile1 B -> buf1; 12 loads/wave
    stage(gA, As, 0, 0); stage(gA, As, 0, 1);
    stage(gB, Bs, 0, 0); stage(gB, Bs, 0, 1);
    stage(gB, Bs + TSZ, 1, 0); stage(gB, Bs + TSZ, 1, 1);
    asm volatile("s_waitcnt vmcnt(4)" ::: "memory");   // tile0 landed; t1.B in flight
    __builtin_amdgcn_s_barrier();

    const int q   = lane >> 4;
    const int c15 = lane & 15;
    f32x4 acc[8][4] = {};

#pragma unroll 2
    for (int t = 0; t < 64; ++t) {
        const int cur = t & 1;
        unsigned short* Ac = As + cur * TSZ;
        unsigned short* Bc = Bs + cur * TSZ;
        unsigned short* An = As + (cur ^ 1) * TSZ;

        // earliest-possible A(t+1) stage: dest An last read during t-1 (< BAR_end(t-1))
        if (t < 63) { stage(gA, An, t + 1, 0); stage(gA, An, t + 1, 1); }

        // B-frags for the whole tile (8 x ds_read_b128), held in regs
        s16x8 bfrag[4][2];
#pragma unroll
        for (int nt = 0; nt < 4; ++nt) {
            const int row = wn * 64 + nt * 16 + c15;
#pragma unroll
            for (int kc = 0; kc < 2; ++kc) {
                const int phys = (kc * 4 + q) ^ (row & 7);
                bfrag[nt][kc] = *(const s16x8*)&Bc[row * 64 + phys * 8];
            }
        }

        // quadrant 0 (mt 0,1): reads af0, consumes ALL bfrag -> retires B reads
        {
            s16x8 af[2][2];
#pragma unroll
            for (int i = 0; i < 2; ++i) {
                const int row = wm * 128 + i * 16 + c15;
#pragma unroll
                for (int kc = 0; kc < 2; ++kc)
                    af[i][kc] = *(const s16x8*)&Ac[row * 64 + ((kc * 4 + q) ^ (row & 7)) * 8];
            }
            __builtin_amdgcn_s_setprio(1);
#pragma unroll
            for (int i = 0; i < 2; ++i)
#pragma unroll
                for (int nt = 0; nt < 4; ++nt)
#pragma unroll
                    for (int kc = 0; kc < 2; ++kc)
                        acc[i][nt] = __builtin_amdgcn_mfma_f32_16x16x32_bf16(
                            af[i][kc], bfrag[nt][kc], acc[i][nt], 0, 0, 0);
            __builtin_amdgcn_s_setprio(0);
        }

        asm volatile("s_waitcnt lgkmcnt(0)" ::: "memory");  // belt+suspenders
        __builtin_amdgcn_s_barrier();                       // BAR_mid

        // B(t+2) stages into Bc (reads of Bc finished before BAR_mid)
        if (t < 62) stage(gB, Bc, t + 2, 0);

        // quadrants 1..3 (mt 2..7), barrier-free; compiler interleaves ds/MFMA
#pragma unroll
        for (int ph = 1; ph < 4; ++ph) {
            if (ph == 2 && t < 62) stage(gB, Bc, t + 2, 1);
            s16x8 af[2][2];
#pragma unroll
            for (int i = 0; i < 2; ++i) {
                const int row = wm * 128 + (ph * 2 + i) * 16 + c15;
#pragma unroll
                for (int kc = 0; kc < 2; ++kc)
                    af[i][kc] = *(const s16x8*)&Ac[row * 64 + ((kc * 4 + q) ^ (row & 7)) * 8];
            }
            __builtin_amdgcn_s_setprio(1);
#pragma unroll
            for (int i = 0; i < 2; ++i)
#pragma unroll
                for (int nt = 0; nt < 4; ++nt)
#pragma unroll
                    for (int kc = 0; kc < 2; ++kc)
                        acc[ph * 2 + i][nt] = __builtin_amdgcn_mfma_f32_16x16x32_bf16(
                            af[i][kc], bfrag[nt][kc], acc[ph * 2 + i][nt], 0, 0, 0);
            __builtin_amdgcn_s_setprio(0);
        }

        if (t < 62) { asm volatile("s_waitcnt vmcnt(4)" ::: "memory"); }
        else        { asm volatile("s_waitcnt vmcnt(0)" ::: "memory"); }
        __builtin_amdgcn_s_barrier();                       // BAR_end
    }

    // epilogue: C/D layout col=lane&15, row=(lane>>4)*4+reg ; scale by mag/norm
#pragma unroll
    for (int nt = 0; nt < 4; ++nt) {
        const int col = tileN + wn * 64 + nt * 16 + c15;
        const float s = scale[col];
#pragma unroll
        for (int mt = 0; mt < 8; ++mt) {
            const int row0 = tileM + wm * 128 + mt * 16 + q * 4;
#pragma unroll
            for (int r = 0; r < 4; ++r)
                out[(size_t)(row0 + r) * 4096 + col] = acc[mt][nt][r] * s;
        }
    }
}

extern "C" void kernel_launch(void* const* d_in, const int* in_sizes, int n_in,
                              void* d_out, int out_size, void* d_ws, size_t ws_size,
                              hipStream_t stream) {
    const float* x   = (const float*)d_in[0];   // [4,2048,4096]
    const float* W   = (const float*)d_in[1];   // [4096,4096]
    const float* A   = (const float*)d_in[2];   // [16,4096]
    const float* B   = (const float*)d_in[3];   // [4096,16]
    const float* mag = (const float*)d_in[4];   // [4096]
    float* out = (float*)d_out;

    const size_t XBF_BYTES = (size_t)8192 * 4096 * 2;  // 67,108,864
    const size_t WBF_BYTES = (size_t)4096 * 4096 * 2;  // 33,554,432
    const size_t NEEDED = XBF_BYTES + WBF_BYTES + 4096 * sizeof(float);
    if (ws_size < NEEDED) return;

    unsigned short* xbf = (unsigned short*)d_ws;
    unsigned short* wbf = (unsigned short*)((char*)d_ws + XBF_BYTES);
    float* scale = (float*)((char*)d_ws + XBF_BYTES + WBF_BYTES);

    cvt_kernel<<<8192, 256, 0, stream>>>((const float4*)x, (us4*)xbf);
    prep_kernel<<<1024, 256, 0, stream>>>((const float4*)W, (const float4*)A,
                                          B, mag, wbf, scale);
    dora_gemm<<<512, 512, 0, stream>>>(xbf, wbf, scale, out);
}